// Round 6
// baseline (974.066 us; speedup 1.0000x reference)
//
#include <hip/hip_runtime.h>
#include <hip/hip_bf16.h>

#define B_N 65536

typedef __attribute__((ext_vector_type(8))) __bf16 bf16x8;
typedef __attribute__((ext_vector_type(8))) unsigned short ushort8;
typedef __attribute__((ext_vector_type(4))) float f32x4;
typedef __attribute__((ext_vector_type(2))) unsigned uintx2;
typedef __attribute__((ext_vector_type(4))) unsigned uintx4;

// ---------- ws layout (bytes) ----------
// 0     : unsigned max|time_delta| bits (atomicMax target; memset to 0 first)
// 64    : WzT  bf16 [128][64]   Wz = W1[0:64,:] transposed
// 16448 : W2T  bf16 [128][128]
// 49216 : W3T  bf16 [64][128]

__device__ __forceinline__ unsigned short f2bf(float f) {
    unsigned u = __float_as_uint(f);
    u += 0x7FFFu + ((u >> 16) & 1u);   // RNE
    return (unsigned short)(u >> 16);
}

#if defined(__has_builtin)
#if __has_builtin(__builtin_amdgcn_cvt_pk_bf16_f32)
#define HAVE_PK_BF16 1
#endif
#endif

#ifdef HAVE_PK_BF16
__device__ __forceinline__ unsigned pk2(float a, float b) {
    return __builtin_bit_cast(unsigned, __builtin_amdgcn_cvt_pk_bf16_f32(a, b));
}
#else
// RNE round both, then v_perm_b32 packs the two high halves in one instr.
__device__ __forceinline__ unsigned pk2(float a, float b) {
    unsigned ua = __float_as_uint(a), ub = __float_as_uint(b);
    ua += 0x7FFFu + ((ua >> 16) & 1u);
    ub += 0x7FFFu + ((ub >> 16) & 1u);
    return __builtin_amdgcn_perm(ub, ua, 0x07060302);  // {ub.hi16, ua.hi16}
}
#endif

// tanh(x) = 1 - 2/(exp2(x*2*log2e)+1): mul, exp2, add, rcp, fma (5 instr)
__device__ __forceinline__ float fast_tanh(float x) {
    float e = __builtin_amdgcn_exp2f(x * 2.88539008177793f);
    return fmaf(-2.0f, __builtin_amdgcn_rcpf(e + 1.0f), 1.0f);
}

// ---------- kernel 1: fused max|td| reduction + weight transpose to bf16 ----------
__global__ void k_prep(const float* __restrict__ td, const float* __restrict__ W1,
                       const float* __restrict__ W2, const float* __restrict__ W3,
                       unsigned* __restrict__ ws) {
    const int stride = gridDim.x * blockDim.x;
    int i0 = blockIdx.x * blockDim.x + threadIdx.x;

    float m = 0.0f;
    for (int i = i0; i < B_N; i += stride) m = fmaxf(m, fabsf(td[i]));
#pragma unroll
    for (int o = 32; o; o >>= 1) m = fmaxf(m, __shfl_down(m, o));
    if ((threadIdx.x & 63) == 0) atomicMax(ws, __float_as_uint(m));

    unsigned short* wsb = (unsigned short*)((char*)ws + 64);
    const int total = 8192 + 16384 + 8192;
    for (int i = i0; i < total; i += stride) {
        float v;
        int o = i;
        if (o < 8192) {                       // WzT[n][k] = W1[k][n]
            int n = o >> 6, k = o & 63;
            v = W1[k * 128 + n];
        } else if (o < 8192 + 16384) {        // W2T[n][k] = W2[k][n]
            o -= 8192;
            int n = o >> 7, k = o & 127;
            v = W2[k * 128 + n];
        } else {                              // W3T[n][k] = W3[k][n]
            o -= 8192 + 16384;
            int n = o >> 7, k = o & 127;
            v = W3[k * 64 + n];
        }
        wsb[i] = f2bf(v);
    }
}

// ---------- kernel 2: the ODE solver ----------
// R5 lesson: with a 128-AGPR W2 cache, regs/wave = 256 -> 2 waves/SIMD and the
// kernel is latency-bound at 217 us regardless of VALU count (R1==R5 time).
// New design: NO register weight cache; all weights in swizzled pad-free LDS;
// block = 1024 threads (16 waves) = 1 block/CU, grid 256 = 1 per CU;
// __launch_bounds__(1024,4) caps regs at 128 -> 4 waves/SIMD (2x occupancy).
// XOR chunk swizzle (16B chunk index ^ row) keeps every b128 access <=2-way.
__launch_bounds__(1024, 4)
__global__ void k_main(const float* __restrict__ z_in, const float* __restrict__ td,
                       const float* __restrict__ W1, const float* __restrict__ b1,
                       const float* __restrict__ b2, const float* __restrict__ b3,
                       const void* __restrict__ ws, float* __restrict__ out) {
    __shared__ __align__(16) unsigned short WzL[128 * 64];     // 16384 B
    __shared__ __align__(16) unsigned short W2L[128 * 128];    // 32768 B
    __shared__ __align__(16) unsigned short W3L[64 * 128];     // 16384 B
    __shared__ __align__(16) unsigned short hS[16][16 * 128];  // 65536 B (per-wave)
    __shared__ __align__(16) float b1tW[16][128];              // 8192 B (per-wave)
    __shared__ __align__(16) float4 pb1wtL[64];                // 1024 B
    __shared__ __align__(16) float b2L[128];                   // 512 B
    __shared__ __align__(16) float b3L[64];                    // 256 B

    const unsigned* wsu = (const unsigned*)ws;
    const unsigned short* wzg = (const unsigned short*)((const char*)ws + 64);
    const unsigned short* w2g = wzg + 8192;
    const unsigned short* w3g = wzg + 24576;

    const int tid = threadIdx.x;   // 0..1023

    {   // stage WzT: 1024 16B-chunks, swizzle chunk c -> c ^ (n&7)
        int n = tid >> 3, c = tid & 7;
        *(ushort8*)&WzL[n * 64 + ((c ^ (n & 7)) << 3)] =
            *(const ushort8*)&wzg[n * 64 + (c << 3)];
    }
    for (int idx = tid; idx < 2048; idx += 1024) {   // stage W2T: 2048 chunks
        int n = idx >> 4, c = idx & 15;
        *(ushort8*)&W2L[n * 128 + ((c ^ (n & 15)) << 3)] =
            *(const ushort8*)&w2g[n * 128 + (c << 3)];
    }
    {   // stage W3T: 1024 chunks
        int n = tid >> 4, c = tid & 15;
        *(ushort8*)&W3L[n * 128 + ((c ^ (n & 15)) << 3)] =
            *(const ushort8*)&w3g[n * 128 + (c << 3)];
    }
    if (tid < 128) b2L[tid] = b2[tid];
    if (tid < 64)  b3L[tid] = b3[tid];
    if (tid < 64) {
        float4 p;
        p.x = b1[tid * 2];
        p.y = b1[tid * 2 + 1];
        p.z = W1[64 * 128 + tid * 2];     // Wt = last row of W1
        p.w = W1[64 * 128 + tid * 2 + 1];
        pb1wtL[tid] = p;
    }
    __syncthreads();   // only barrier; waves independent afterwards

    const float maxab = __uint_as_float(wsu[0]);
    const int steps = (int)ceil((double)maxab / 0.1);

    const int wave = tid >> 6;
    const int lane = tid & 63;
    const int q = lane >> 4;
    const int b = lane & 15;                  // batch row (B/C/D) == weight row (A)
    const int row = blockIdx.x * 256 + wave * 16 + b;
    unsigned short* hw = hS[wave];
    float* b1t = b1tW[wave];

    // z state in fp32, B-fragment layout: zr[kt*8+j] = z[row][kt*32 + q*8 + j]
    float zr[16];
#pragma unroll
    for (int kt = 0; kt < 2; ++kt) {
        const float4* p = (const float4*)(z_in + (size_t)row * 64 + kt * 32 + q * 8);
        float4 a = p[0], c = p[1];
        zr[kt * 8 + 0] = a.x; zr[kt * 8 + 1] = a.y; zr[kt * 8 + 2] = a.z; zr[kt * 8 + 3] = a.w;
        zr[kt * 8 + 4] = c.x; zr[kt * 8 + 5] = c.y; zr[kt * 8 + 6] = c.z; zr[kt * 8 + 7] = c.w;
    }
    const float dtr = (steps > 0) ? (td[row] / (float)steps) : 0.0f;

    for (int s = 0; s < steps; ++s) {
        const float t = (float)s * 0.1f;

        // per-step layer-1 bias vector into per-wave LDS (in-wave coherent)
        {
            float4 pb = pb1wtL[lane];
            float2 bt;
            bt.x = fmaf(t, pb.z, pb.x);
            bt.y = fmaf(t, pb.w, pb.y);
            *(float2*)&b1t[lane * 2] = bt;
        }

        // z -> bf16 B-fragments
        bf16x8 zB[2];
#pragma unroll
        for (int kt = 0; kt < 2; ++kt) {
            uintx4 u;
            u[0] = pk2(zr[kt * 8 + 0], zr[kt * 8 + 1]);
            u[1] = pk2(zr[kt * 8 + 2], zr[kt * 8 + 3]);
            u[2] = pk2(zr[kt * 8 + 4], zr[kt * 8 + 5]);
            u[3] = pk2(zr[kt * 8 + 6], zr[kt * 8 + 7]);
            zB[kt] = __builtin_bit_cast(bf16x8, u);
        }

        // ---- layer 1: h1^T tiles = WzT * z^T + b1t ----
#pragma unroll
        for (int n0 = 0; n0 < 8; ++n0) {
            f32x4 acc = *(const f32x4*)&b1t[n0 * 16 + q * 4];   // broadcast read
#pragma unroll
            for (int kt = 0; kt < 2; ++kt) {
                bf16x8 wf = __builtin_bit_cast(
                    bf16x8,
                    *(const ushort8*)&WzL[(n0 * 16 + b) * 64 + (((kt * 4 + q) ^ (b & 7)) << 3)]);
                acc = __builtin_amdgcn_mfma_f32_16x16x32_bf16(wf, zB[kt], acc, 0, 0, 0);
            }
            uintx2 pw;
            pw[0] = pk2(fast_tanh(acc[0]), fast_tanh(acc[1]));
            pw[1] = pk2(fast_tanh(acc[2]), fast_tanh(acc[3]));
            // logical chunk c = n0*2 + (q>>1), stored at c^b, +8B for odd q
            *(uintx2*)&hw[b * 128 + (((n0 * 2 + (q >> 1)) ^ b) << 3) + ((q & 1) << 2)] = pw;
        }

        // ---- layer 2: h2^T = W2T * h1^T + b2 ----
        bf16x8 hB[4];
#pragma unroll
        for (int kt = 0; kt < 4; ++kt)
            hB[kt] = __builtin_bit_cast(
                bf16x8, *(const ushort8*)&hw[b * 128 + (((kt * 4 + q) ^ b) << 3)]);
#pragma unroll
        for (int n0 = 0; n0 < 8; ++n0) {
            f32x4 acc = *(const f32x4*)&b2L[n0 * 16 + q * 4];   // broadcast read
#pragma unroll
            for (int kt = 0; kt < 4; ++kt) {
                bf16x8 wf = __builtin_bit_cast(
                    bf16x8,
                    *(const ushort8*)&W2L[(n0 * 16 + b) * 128 + (((kt * 4 + q) ^ b) << 3)]);
                acc = __builtin_amdgcn_mfma_f32_16x16x32_bf16(wf, hB[kt], acc, 0, 0, 0);
            }
            uintx2 pw;
            pw[0] = pk2(fast_tanh(acc[0]), fast_tanh(acc[1]));
            pw[1] = pk2(fast_tanh(acc[2]), fast_tanh(acc[3]));
            *(uintx2*)&hw[b * 128 + (((n0 * 2 + (q >> 1)) ^ b) << 3) + ((q & 1) << 2)] = pw;
        }

        // ---- layer 3: dz^T = W3T * h2^T + b3 (overlays hS; gB read first) ----
        bf16x8 gB[4];
#pragma unroll
        for (int kt = 0; kt < 4; ++kt)
            gB[kt] = __builtin_bit_cast(
                bf16x8, *(const ushort8*)&hw[b * 128 + (((kt * 4 + q) ^ b) << 3)]);
#pragma unroll
        for (int n0 = 0; n0 < 4; ++n0) {
            f32x4 acc = *(const f32x4*)&b3L[n0 * 16 + q * 4];   // broadcast read
#pragma unroll
            for (int kt = 0; kt < 4; ++kt) {
                bf16x8 wf = __builtin_bit_cast(
                    bf16x8,
                    *(const ushort8*)&W3L[(n0 * 16 + b) * 128 + (((kt * 4 + q) ^ b) << 3)]);
                acc = __builtin_amdgcn_mfma_f32_16x16x32_bf16(wf, gB[kt], acc, 0, 0, 0);
            }
            uintx2 pw;
            pw[0] = pk2(acc[0], acc[1]);
            pw[1] = pk2(acc[2], acc[3]);
            *(uintx2*)&hw[b * 128 + (((n0 * 2 + (q >> 1)) ^ b) << 3) + ((q & 1) << 2)] = pw;
        }

        // ---- z += dz * actual_dt ----
#pragma unroll
        for (int kt = 0; kt < 2; ++kt) {
            ushort8 dzb = *(const ushort8*)&hw[b * 128 + (((kt * 4 + q) ^ b) << 3)];
#pragma unroll
            for (int j = 0; j < 8; ++j)
                zr[kt * 8 + j] = fmaf(__uint_as_float(((unsigned)dzb[j]) << 16), dtr,
                                      zr[kt * 8 + j]);
        }
    }

    // store final z
#pragma unroll
    for (int kt = 0; kt < 2; ++kt) {
        float4 a, c;
        a.x = zr[kt * 8 + 0]; a.y = zr[kt * 8 + 1]; a.z = zr[kt * 8 + 2]; a.w = zr[kt * 8 + 3];
        c.x = zr[kt * 8 + 4]; c.y = zr[kt * 8 + 5]; c.z = zr[kt * 8 + 6]; c.w = zr[kt * 8 + 7];
        float4* p = (float4*)(out + (size_t)row * 64 + kt * 32 + q * 8);
        p[0] = a; p[1] = c;
    }
}

extern "C" void kernel_launch(void* const* d_in, const int* in_sizes, int n_in,
                              void* d_out, int out_size, void* d_ws, size_t ws_size,
                              hipStream_t stream) {
    const float* z  = (const float*)d_in[0];
    const float* td = (const float*)d_in[1];
    const float* W1 = (const float*)d_in[2];
    const float* b1 = (const float*)d_in[3];
    const float* W2 = (const float*)d_in[4];
    const float* b2 = (const float*)d_in[5];
    const float* W3 = (const float*)d_in[6];
    const float* b3 = (const float*)d_in[7];
    float* out = (float*)d_out;
    (void)in_sizes; (void)n_in; (void)out_size; (void)ws_size;

    hipMemsetAsync(d_ws, 0, 64, stream);
    k_prep<<<64, 256, 0, stream>>>(td, W1, W2, W3, (unsigned*)d_ws);
    k_main<<<256, 1024, 0, stream>>>(z, td, W1, b1, b2, b3, d_ws, out);
}